// Round 1
// baseline (2796.070 us; speedup 1.0000x reference)
//
#include <hip/hip_runtime.h>

#define D 128  // D_IN == D_OUT == 128

// ---------------------------------------------------------------------------
// Kernel 1: support = x @ W   (fp32, vector ALU — no fp32 MFMA on CDNA4)
// Block = 256 threads. W (128x128 fp32 = 64 KB) staged once in LDS.
// Thread tile: 4 rows x 4 cols. x rows read directly from global: each
// float4 is read by the 32 threads of a col-group at the SAME address ->
// single coalesced/broadcast transaction, x traffic = 51.2 MB total.
// ---------------------------------------------------------------------------
__global__ __launch_bounds__(256) void gemm_xw(const float* __restrict__ x,
                                               const float* __restrict__ W,
                                               float* __restrict__ sup,
                                               int N) {
    __shared__ float4 Ws[D][32];  // Ws[k][c4] = W[k][4c4..4c4+3], 64 KB
    const int tid = threadIdx.x;
    const float4* W4 = (const float4*)W;
    for (int i = tid; i < D * 32; i += 256) ((float4*)Ws)[i] = W4[i];
    __syncthreads();

    const int cg = tid & 31;   // col group: cols 4*cg .. 4*cg+3
    const int rg = tid >> 5;   // row group 0..7
    const int row0 = blockIdx.x * 32 + rg * 4;
    if (row0 >= N) return;

    if (row0 + 4 <= N) {
        const float4* x4 = (const float4*)(x + (size_t)row0 * D);  // 4 rows x 32 float4
        float4 a0 = {0, 0, 0, 0}, a1 = a0, a2 = a0, a3 = a0;
#pragma unroll 8
        for (int k4 = 0; k4 < 32; ++k4) {
            float4 w0 = Ws[k4 * 4 + 0][cg];
            float4 w1 = Ws[k4 * 4 + 1][cg];
            float4 w2 = Ws[k4 * 4 + 2][cg];
            float4 w3 = Ws[k4 * 4 + 3][cg];
            float4 xv;
#define ACC(a, xr)                                                      \
            xv = x4[(xr) * 32 + k4];                                    \
            a.x += xv.x * w0.x + xv.y * w1.x + xv.z * w2.x + xv.w * w3.x; \
            a.y += xv.x * w0.y + xv.y * w1.y + xv.z * w2.y + xv.w * w3.y; \
            a.z += xv.x * w0.z + xv.y * w1.z + xv.z * w2.z + xv.w * w3.z; \
            a.w += xv.x * w0.w + xv.y * w1.w + xv.z * w2.w + xv.w * w3.w
            ACC(a0, 0);
            ACC(a1, 1);
            ACC(a2, 2);
            ACC(a3, 3);
#undef ACC
        }
        float4* s4 = (float4*)(sup + (size_t)row0 * D);
        s4[0 * 32 + cg] = a0;
        s4[1 * 32 + cg] = a1;
        s4[2 * 32 + cg] = a2;
        s4[3 * 32 + cg] = a3;
    } else {
        // generic tail (not hit for N=100000, kept for safety)
        for (int r = 0; r < N - row0; ++r) {
            const float* xr = x + (size_t)(row0 + r) * D;
            float4 a = {0, 0, 0, 0};
            for (int k = 0; k < D; ++k) {
                float xv = xr[k];
                float4 w = Ws[k][cg];
                a.x += xv * w.x; a.y += xv * w.y; a.z += xv * w.z; a.w += xv * w.w;
            }
            ((float4*)(sup + (size_t)(row0 + r) * D))[cg] = a;
        }
    }
}

// ---------------------------------------------------------------------------
// Kernel 2: out[n][d] = b[d]   (bias init; harness poisons d_out)
// ---------------------------------------------------------------------------
__global__ __launch_bounds__(256) void init_out(const float* __restrict__ b,
                                                float* __restrict__ out,
                                                long total4) {
    const float4* b4 = (const float4*)b;
    long i = (long)blockIdx.x * blockDim.x + threadIdx.x;
    long stride = (long)gridDim.x * blockDim.x;
    for (; i < total4; i += stride) ((float4*)out)[i] = b4[i & 31];
}

// ---------------------------------------------------------------------------
// Kernel 3: edge scatter. 32 threads per edge, one float4 each.
// out[row[e]][:] += vals[e] * support[col[e]][:]   via 4 fp32 atomics/thread.
// ---------------------------------------------------------------------------
__global__ __launch_bounds__(256) void scatter_edges(const float* __restrict__ sup,
                                                     const int* __restrict__ row,
                                                     const int* __restrict__ col,
                                                     const float* __restrict__ vals,
                                                     float* __restrict__ out,
                                                     int E) {
    long gid = (long)blockIdx.x * 256 + threadIdx.x;
    int e = (int)(gid >> 5);
    if (e >= E) return;
    int p = (int)(gid & 31);

    int r = row[e];
    int c = col[e];
    float v = vals[e];

    float4 s = ((const float4*)sup)[(size_t)c * 32 + p];
    float* o = out + (size_t)r * D + (size_t)p * 4;
    atomicAdd(o + 0, v * s.x);
    atomicAdd(o + 1, v * s.y);
    atomicAdd(o + 2, v * s.z);
    atomicAdd(o + 3, v * s.w);
}

extern "C" void kernel_launch(void* const* d_in, const int* in_sizes, int n_in,
                              void* d_out, int out_size, void* d_ws, size_t ws_size,
                              hipStream_t stream) {
    const float* x    = (const float*)d_in[0];
    const float* W    = (const float*)d_in[1];
    const float* b    = (const float*)d_in[2];
    const int*   row  = (const int*)d_in[3];
    const int*   col  = (const int*)d_in[4];
    const float* vals = (const float*)d_in[5];
    float* out = (float*)d_out;

    const int N = in_sizes[0] / D;
    const int E = in_sizes[3];

    float* sup = (float*)d_ws;  // N*128 fp32 = 51.2 MB scratch

    gemm_xw<<<(N + 31) / 32, 256, 0, stream>>>(x, W, sup, N);
    init_out<<<2048, 256, 0, stream>>>(b, out, (long)N * (D / 4));
    long sthreads = (long)E * 32;
    scatter_edges<<<(int)((sthreads + 255) / 256), 256, 0, stream>>>(sup, row, col, vals, out, E);
}

// Round 2
// 565.093 us; speedup vs baseline: 4.9480x; 4.9480x over previous
//
#include <hip/hip_runtime.h>

#define D 128  // D_IN == D_OUT == 128

// ---------------------------------------------------------------------------
// Kernel 1: support = x @ W   (fp32, vector ALU — no fp32 MFMA on CDNA4)
// ---------------------------------------------------------------------------
__global__ __launch_bounds__(256) void gemm_xw(const float* __restrict__ x,
                                               const float* __restrict__ W,
                                               float* __restrict__ sup,
                                               int N) {
    __shared__ float4 Ws[D][32];  // 64 KB
    const int tid = threadIdx.x;
    const float4* W4 = (const float4*)W;
    for (int i = tid; i < D * 32; i += 256) ((float4*)Ws)[i] = W4[i];
    __syncthreads();

    const int cg = tid & 31;
    const int rg = tid >> 5;
    const int row0 = blockIdx.x * 32 + rg * 4;
    if (row0 >= N) return;

    if (row0 + 4 <= N) {
        const float4* x4 = (const float4*)(x + (size_t)row0 * D);
        float4 a0 = {0, 0, 0, 0}, a1 = a0, a2 = a0, a3 = a0;
#pragma unroll 8
        for (int k4 = 0; k4 < 32; ++k4) {
            float4 w0 = Ws[k4 * 4 + 0][cg];
            float4 w1 = Ws[k4 * 4 + 1][cg];
            float4 w2 = Ws[k4 * 4 + 2][cg];
            float4 w3 = Ws[k4 * 4 + 3][cg];
            float4 xv;
#define ACC(a, xr)                                                      \
            xv = x4[(xr) * 32 + k4];                                    \
            a.x += xv.x * w0.x + xv.y * w1.x + xv.z * w2.x + xv.w * w3.x; \
            a.y += xv.x * w0.y + xv.y * w1.y + xv.z * w2.y + xv.w * w3.y; \
            a.z += xv.x * w0.z + xv.y * w1.z + xv.z * w2.z + xv.w * w3.z; \
            a.w += xv.x * w0.w + xv.y * w1.w + xv.z * w2.w + xv.w * w3.w
            ACC(a0, 0);
            ACC(a1, 1);
            ACC(a2, 2);
            ACC(a3, 3);
#undef ACC
        }
        float4* s4 = (float4*)(sup + (size_t)row0 * D);
        s4[0 * 32 + cg] = a0;
        s4[1 * 32 + cg] = a1;
        s4[2 * 32 + cg] = a2;
        s4[3 * 32 + cg] = a3;
    } else {
        for (int r = 0; r < N - row0; ++r) {
            const float* xr = x + (size_t)(row0 + r) * D;
            float4 a = {0, 0, 0, 0};
            for (int k = 0; k < D; ++k) {
                float xv = xr[k];
                float4 w = Ws[k][cg];
                a.x += xv * w.x; a.y += xv * w.y; a.z += xv * w.z; a.w += xv * w.w;
            }
            ((float4*)(sup + (size_t)(row0 + r) * D))[cg] = a;
        }
    }
}

// ---------------------------------------------------------------------------
// Kernel 2: histogram of destination rows (int atomics, cnt pre-zeroed)
// ---------------------------------------------------------------------------
__global__ __launch_bounds__(256) void hist_rows(const int* __restrict__ row,
                                                 int* __restrict__ cnt, int E) {
    int i = blockIdx.x * 256 + threadIdx.x;
    int stride = gridDim.x * 256;
    for (; i < E; i += stride) atomicAdd(&cnt[row[i]], 1);
}

// ---------------------------------------------------------------------------
// Kernel 3: exclusive scan of cnt[0..N) -> rowstart[0..N], copy to cursor.
// Single block, 1024 threads (16 waves), chunked.
// ---------------------------------------------------------------------------
__global__ __launch_bounds__(1024) void scan_rows(const int* __restrict__ cnt,
                                                  int* __restrict__ rowstart,
                                                  int* __restrict__ cursor, int N) {
    __shared__ int wsum[16];
    __shared__ int carry;
    const int tid = threadIdx.x;
    const int lane = tid & 63;
    const int wid = tid >> 6;
    if (tid == 0) carry = 0;
    __syncthreads();
    for (int base = 0; base < N; base += 1024) {
        int i = base + tid;
        int v = (i < N) ? cnt[i] : 0;
        int s = v;
#pragma unroll
        for (int off = 1; off < 64; off <<= 1) {
            int t = __shfl_up(s, off, 64);
            if (lane >= off) s += t;
        }
        if (lane == 63) wsum[wid] = s;
        __syncthreads();
        if (wid == 0 && lane < 16) {
            int ws = wsum[lane];
#pragma unroll
            for (int off = 1; off < 16; off <<= 1) {
                int t = __shfl_up(ws, off, 64);
                if (lane >= off) ws += t;
            }
            wsum[lane] = ws;  // inclusive over wave sums
        }
        __syncthreads();
        int waveoff = (wid == 0) ? 0 : wsum[wid - 1];
        int excl = carry + waveoff + (s - v);
        if (i < N) { rowstart[i] = excl; cursor[i] = excl; }
        __syncthreads();
        if (tid == 1023) carry += waveoff + s;  // chunk total
        __syncthreads();
    }
    if (tid == 0) rowstart[N] = carry;
}

// ---------------------------------------------------------------------------
// Kernel 4: bucket fill — pairs[pos] = (col, val) grouped by destination row
// ---------------------------------------------------------------------------
__global__ __launch_bounds__(256) void fill_csr(const int* __restrict__ row,
                                                const int* __restrict__ col,
                                                const float* __restrict__ vals,
                                                int* __restrict__ cursor,
                                                int2* __restrict__ pairs, int E) {
    int i = blockIdx.x * 256 + threadIdx.x;
    int stride = gridDim.x * 256;
    for (; i < E; i += stride) {
        int r = row[i];
        int pos = atomicAdd(&cursor[r], 1);
        int2 pk;
        pk.x = col[i];
        pk.y = __float_as_int(vals[i]);
        pairs[pos] = pk;
    }
}

// ---------------------------------------------------------------------------
// Kernel 5: pull — one wave per output row, zero fp atomics.
// out[r] = b + sum_j vals_j * sup[col_j];  float2 per lane (64 lanes = 128).
// ---------------------------------------------------------------------------
__global__ __launch_bounds__(256) void pull_rows(const float* __restrict__ sup,
                                                 const int2* __restrict__ pairs,
                                                 const int* __restrict__ rowstart,
                                                 const float* __restrict__ b,
                                                 float* __restrict__ out, int N) {
    int r = blockIdx.x * 4 + (threadIdx.x >> 6);
    if (r >= N) return;
    int lane = threadIdx.x & 63;
    int s = rowstart[r];
    int e = rowstart[r + 1];
    float2 acc = ((const float2*)b)[lane];
    for (int j = s; j < e; ++j) {
        int2 pk = pairs[j];                    // wave-uniform address -> broadcast
        float v = __int_as_float(pk.y);
        float2 sv = ((const float2*)(sup + (size_t)pk.x * D))[lane];
        acc.x += v * sv.x;
        acc.y += v * sv.y;
    }
    ((float2*)(out + (size_t)r * D))[lane] = acc;
}

// ---------------------------------------------------------------------------
// Fallback (ws too small): atomic scatter (round-1 path)
// ---------------------------------------------------------------------------
__global__ __launch_bounds__(256) void init_out(const float* __restrict__ b,
                                                float* __restrict__ out,
                                                long total4) {
    const float4* b4 = (const float4*)b;
    long i = (long)blockIdx.x * blockDim.x + threadIdx.x;
    long stride = (long)gridDim.x * blockDim.x;
    for (; i < total4; i += stride) ((float4*)out)[i] = b4[i & 31];
}

__global__ __launch_bounds__(256) void scatter_edges(const float* __restrict__ sup,
                                                     const int* __restrict__ row,
                                                     const int* __restrict__ col,
                                                     const float* __restrict__ vals,
                                                     float* __restrict__ out, int E) {
    long gid = (long)blockIdx.x * 256 + threadIdx.x;
    int e = (int)(gid >> 5);
    if (e >= E) return;
    int p = (int)(gid & 31);
    int r = row[e];
    int c = col[e];
    float v = vals[e];
    float4 s = ((const float4*)sup)[(size_t)c * 32 + p];
    float* o = out + (size_t)r * D + (size_t)p * 4;
    atomicAdd(o + 0, v * s.x);
    atomicAdd(o + 1, v * s.y);
    atomicAdd(o + 2, v * s.z);
    atomicAdd(o + 3, v * s.w);
}

extern "C" void kernel_launch(void* const* d_in, const int* in_sizes, int n_in,
                              void* d_out, int out_size, void* d_ws, size_t ws_size,
                              hipStream_t stream) {
    const float* x    = (const float*)d_in[0];
    const float* W    = (const float*)d_in[1];
    const float* b    = (const float*)d_in[2];
    const int*   row  = (const int*)d_in[3];
    const int*   col  = (const int*)d_in[4];
    const float* vals = (const float*)d_in[5];
    float* out = (float*)d_out;

    const int N = in_sizes[0] / D;
    const int E = in_sizes[3];

    // workspace layout
    char* base = (char*)d_ws;
    size_t off = 0;
    float* sup = (float*)(base + off);           off += (size_t)N * D * sizeof(float);
    int* cnt      = (int*)(base + off);          off += (size_t)N * sizeof(int);
    int* rowstart = (int*)(base + off);          off += (size_t)(N + 1) * sizeof(int);
    int* cursor   = (int*)(base + off);          off += (size_t)N * sizeof(int);
    off = (off + 7) & ~(size_t)7;
    int2* pairs   = (int2*)(base + off);         off += (size_t)E * sizeof(int2);
    const bool csr_ok = (off <= ws_size);

    gemm_xw<<<(N + 31) / 32, 256, 0, stream>>>(x, W, sup, N);

    if (csr_ok) {
        hipMemsetAsync(cnt, 0, (size_t)N * sizeof(int), stream);
        hist_rows<<<2048, 256, 0, stream>>>(row, cnt, E);
        scan_rows<<<1, 1024, 0, stream>>>(cnt, rowstart, cursor, N);
        fill_csr<<<4096, 256, 0, stream>>>(row, col, vals, cursor, pairs, E);
        pull_rows<<<(N + 3) / 4, 256, 0, stream>>>(sup, pairs, rowstart, b, out, N);
    } else {
        init_out<<<2048, 256, 0, stream>>>(b, out, (long)N * (D / 4));
        long sthreads = (long)E * 32;
        scatter_edges<<<(int)((sthreads + 255) / 256), 256, 0, stream>>>(sup, row, col, vals, out, E);
    }
}

// Round 3
// 329.313 us; speedup vs baseline: 8.4906x; 1.7160x over previous
//
#include <hip/hip_runtime.h>

#define D 128  // D_IN == D_OUT == 128

// ---------------------------------------------------------------------------
// Kernel 1: support = x @ W   (fp32, vector ALU — no fp32 MFMA on CDNA4)
// ---------------------------------------------------------------------------
__global__ __launch_bounds__(256) void gemm_xw(const float* __restrict__ x,
                                               const float* __restrict__ W,
                                               float* __restrict__ sup,
                                               int N) {
    __shared__ float4 Ws[D][32];  // 64 KB
    const int tid = threadIdx.x;
    const float4* W4 = (const float4*)W;
    for (int i = tid; i < D * 32; i += 256) ((float4*)Ws)[i] = W4[i];
    __syncthreads();

    const int cg = tid & 31;
    const int rg = tid >> 5;
    const int row0 = blockIdx.x * 32 + rg * 4;
    if (row0 >= N) return;

    if (row0 + 4 <= N) {
        const float4* x4 = (const float4*)(x + (size_t)row0 * D);
        float4 a0 = {0, 0, 0, 0}, a1 = a0, a2 = a0, a3 = a0;
#pragma unroll 8
        for (int k4 = 0; k4 < 32; ++k4) {
            float4 w0 = Ws[k4 * 4 + 0][cg];
            float4 w1 = Ws[k4 * 4 + 1][cg];
            float4 w2 = Ws[k4 * 4 + 2][cg];
            float4 w3 = Ws[k4 * 4 + 3][cg];
            float4 xv;
#define ACC(a, xr)                                                      \
            xv = x4[(xr) * 32 + k4];                                    \
            a.x += xv.x * w0.x + xv.y * w1.x + xv.z * w2.x + xv.w * w3.x; \
            a.y += xv.x * w0.y + xv.y * w1.y + xv.z * w2.y + xv.w * w3.y; \
            a.z += xv.x * w0.z + xv.y * w1.z + xv.z * w2.z + xv.w * w3.z; \
            a.w += xv.x * w0.w + xv.y * w1.w + xv.z * w2.w + xv.w * w3.w
            ACC(a0, 0);
            ACC(a1, 1);
            ACC(a2, 2);
            ACC(a3, 3);
#undef ACC
        }
        float4* s4 = (float4*)(sup + (size_t)row0 * D);
        s4[0 * 32 + cg] = a0;
        s4[1 * 32 + cg] = a1;
        s4[2 * 32 + cg] = a2;
        s4[3 * 32 + cg] = a3;
    } else {
        for (int r = 0; r < N - row0; ++r) {
            const float* xr = x + (size_t)(row0 + r) * D;
            float4 a = {0, 0, 0, 0};
            for (int k = 0; k < D; ++k) {
                float xv = xr[k];
                float4 w = Ws[k][cg];
                a.x += xv * w.x; a.y += xv * w.y; a.z += xv * w.z; a.w += xv * w.w;
            }
            ((float4*)(sup + (size_t)(row0 + r) * D))[cg] = a;
        }
    }
}

// ---------------------------------------------------------------------------
// Kernel 2: histogram + per-edge rank.  rank[e] = arrival index within row.
// ---------------------------------------------------------------------------
__global__ __launch_bounds__(256) void hist_rows(const int* __restrict__ row,
                                                 int* __restrict__ cnt,
                                                 int* __restrict__ rank, int E) {
    int i = blockIdx.x * 256 + threadIdx.x;
    int stride = gridDim.x * 256;
    for (; i < E; i += stride) rank[i] = atomicAdd(&cnt[row[i]], 1);
}

// ---------------------------------------------------------------------------
// Kernel 3a/3b/3c: multi-block exclusive scan of cnt -> rowstart.
// pass1: per-1024-block local exclusive scan + block sum
// pass2: single block scans the (<=1024) block sums, writes rowstart[N]=E
// pass3: add block offsets
// ---------------------------------------------------------------------------
__device__ __forceinline__ int block_scan_1024(int v, int* wsum) {
    // returns inclusive scan of v over the 1024-thread block; wsum[15] = total
    const int tid = threadIdx.x, lane = tid & 63, wid = tid >> 6;
    int s = v;
#pragma unroll
    for (int off = 1; off < 64; off <<= 1) {
        int t = __shfl_up(s, off, 64);
        if (lane >= off) s += t;
    }
    if (lane == 63) wsum[wid] = s;
    __syncthreads();
    if (wid == 0 && lane < 16) {
        int ws = wsum[lane];
#pragma unroll
        for (int off = 1; off < 16; off <<= 1) {
            int t = __shfl_up(ws, off, 64);
            if (lane >= off) ws += t;
        }
        wsum[lane] = ws;
    }
    __syncthreads();
    int waveoff = (wid == 0) ? 0 : wsum[wid - 1];
    return waveoff + s;
}

__global__ __launch_bounds__(1024) void scan_pass1(const int* __restrict__ cnt,
                                                   int* __restrict__ excl,
                                                   int* __restrict__ bsum, int N) {
    __shared__ int wsum[16];
    int i = blockIdx.x * 1024 + threadIdx.x;
    int v = (i < N) ? cnt[i] : 0;
    int incl = block_scan_1024(v, wsum);
    if (i < N) excl[i] = incl - v;
    if (threadIdx.x == 0) bsum[blockIdx.x] = wsum[15];
}

__global__ __launch_bounds__(1024) void scan_pass2(int* __restrict__ bsum,
                                                   int* __restrict__ rowN, int NB) {
    __shared__ int wsum[16];
    int tid = threadIdx.x;
    int v = (tid < NB) ? bsum[tid] : 0;
    int incl = block_scan_1024(v, wsum);
    if (tid < NB) bsum[tid] = incl - v;  // in-place exclusive (reads done pre-sync)
    if (tid == 0) *rowN = wsum[15];      // total = E
}

__global__ __launch_bounds__(256) void scan_pass3(int* __restrict__ excl,
                                                  const int* __restrict__ bsum, int N) {
    int i = blockIdx.x * 256 + threadIdx.x;
    int stride = gridDim.x * 256;
    for (; i < N; i += stride) excl[i] += bsum[i >> 10];
}

// ---------------------------------------------------------------------------
// Kernel 4: bucket fill (atomic-free) — pairs[rowstart[r]+rank[e]] = (col,val)
// ---------------------------------------------------------------------------
__global__ __launch_bounds__(256) void fill_csr(const int* __restrict__ row,
                                                const int* __restrict__ col,
                                                const float* __restrict__ vals,
                                                const int* __restrict__ rowstart,
                                                const int* __restrict__ rank,
                                                int2* __restrict__ pairs, int E) {
    int i = blockIdx.x * 256 + threadIdx.x;
    int stride = gridDim.x * 256;
    for (; i < E; i += stride) {
        int r = row[i];
        int pos = rowstart[r] + rank[i];
        int2 pk;
        pk.x = col[i];
        pk.y = __float_as_int(vals[i]);
        pairs[pos] = pk;
    }
}

// ---------------------------------------------------------------------------
// Kernel 5: pull — one wave per output row, zero fp atomics.
// Wave loads up to 64 (col,val) pairs coalesced (one per lane), broadcasts
// via shfl; support gathers unrolled x4 so 4 loads are in flight.
// ---------------------------------------------------------------------------
__global__ __launch_bounds__(256) void pull_rows(const float* __restrict__ sup,
                                                 const int2* __restrict__ pairs,
                                                 const int* __restrict__ rowstart,
                                                 const float* __restrict__ b,
                                                 float* __restrict__ out, int N) {
    int r = blockIdx.x * 4 + (threadIdx.x >> 6);
    if (r >= N) return;
    int lane = threadIdx.x & 63;
    int s = rowstart[r];
    int e = rowstart[r + 1];
    float2 acc = ((const float2*)b)[lane];

    for (int jb = s; jb < e; jb += 64) {
        int nb = min(64, e - jb);
        int2 pk = {0, 0};
        if (lane < nb) pk = pairs[jb + lane];

        int j = 0;
        for (; j + 4 <= nb; j += 4) {
            int c0 = __shfl(pk.x, j + 0, 64);
            int c1 = __shfl(pk.x, j + 1, 64);
            int c2 = __shfl(pk.x, j + 2, 64);
            int c3 = __shfl(pk.x, j + 3, 64);
            float v0 = __int_as_float(__shfl(pk.y, j + 0, 64));
            float v1 = __int_as_float(__shfl(pk.y, j + 1, 64));
            float v2 = __int_as_float(__shfl(pk.y, j + 2, 64));
            float v3 = __int_as_float(__shfl(pk.y, j + 3, 64));
            float2 s0 = ((const float2*)(sup + (size_t)c0 * D))[lane];
            float2 s1 = ((const float2*)(sup + (size_t)c1 * D))[lane];
            float2 s2 = ((const float2*)(sup + (size_t)c2 * D))[lane];
            float2 s3 = ((const float2*)(sup + (size_t)c3 * D))[lane];
            acc.x += v0 * s0.x; acc.y += v0 * s0.y;
            acc.x += v1 * s1.x; acc.y += v1 * s1.y;
            acc.x += v2 * s2.x; acc.y += v2 * s2.y;
            acc.x += v3 * s3.x; acc.y += v3 * s3.y;
        }
        for (; j < nb; ++j) {
            int c = __shfl(pk.x, j, 64);
            float v = __int_as_float(__shfl(pk.y, j, 64));
            float2 sv = ((const float2*)(sup + (size_t)c * D))[lane];
            acc.x += v * sv.x;
            acc.y += v * sv.y;
        }
    }
    ((float2*)(out + (size_t)r * D))[lane] = acc;
}

// ---------------------------------------------------------------------------
// Fallback (ws too small): atomic scatter (round-1 path)
// ---------------------------------------------------------------------------
__global__ __launch_bounds__(256) void init_out(const float* __restrict__ b,
                                                float* __restrict__ out,
                                                long total4) {
    const float4* b4 = (const float4*)b;
    long i = (long)blockIdx.x * blockDim.x + threadIdx.x;
    long stride = (long)gridDim.x * blockDim.x;
    for (; i < total4; i += stride) ((float4*)out)[i] = b4[i & 31];
}

__global__ __launch_bounds__(256) void scatter_edges(const float* __restrict__ sup,
                                                     const int* __restrict__ row,
                                                     const int* __restrict__ col,
                                                     const float* __restrict__ vals,
                                                     float* __restrict__ out, int E) {
    long gid = (long)blockIdx.x * 256 + threadIdx.x;
    int e = (int)(gid >> 5);
    if (e >= E) return;
    int p = (int)(gid & 31);
    int r = row[e];
    int c = col[e];
    float v = vals[e];
    float4 s = ((const float4*)sup)[(size_t)c * 32 + p];
    float* o = out + (size_t)r * D + (size_t)p * 4;
    atomicAdd(o + 0, v * s.x);
    atomicAdd(o + 1, v * s.y);
    atomicAdd(o + 2, v * s.z);
    atomicAdd(o + 3, v * s.w);
}

extern "C" void kernel_launch(void* const* d_in, const int* in_sizes, int n_in,
                              void* d_out, int out_size, void* d_ws, size_t ws_size,
                              hipStream_t stream) {
    const float* x    = (const float*)d_in[0];
    const float* W    = (const float*)d_in[1];
    const float* b    = (const float*)d_in[2];
    const int*   row  = (const int*)d_in[3];
    const int*   col  = (const int*)d_in[4];
    const float* vals = (const float*)d_in[5];
    float* out = (float*)d_out;

    const int N = in_sizes[0] / D;
    const int E = in_sizes[3];
    const int NB = (N + 1023) / 1024;  // scan blocks (<= 1024 required)

    // workspace layout
    char* base = (char*)d_ws;
    size_t off = 0;
    float* sup    = (float*)(base + off);  off += (size_t)N * D * sizeof(float);
    int* cnt      = (int*)(base + off);    off += (size_t)N * sizeof(int);
    int* rowstart = (int*)(base + off);    off += (size_t)(N + 1) * sizeof(int);
    int* bsum     = (int*)(base + off);    off += (size_t)((NB + 1023) & ~1023) * sizeof(int);
    int* rank     = (int*)(base + off);    off += (size_t)E * sizeof(int);
    off = (off + 7) & ~(size_t)7;
    int2* pairs   = (int2*)(base + off);   off += (size_t)E * sizeof(int2);
    const bool csr_ok = (off <= ws_size) && (NB <= 1024);

    gemm_xw<<<(N + 31) / 32, 256, 0, stream>>>(x, W, sup, N);

    if (csr_ok) {
        hipMemsetAsync(cnt, 0, (size_t)N * sizeof(int), stream);
        hist_rows<<<2048, 256, 0, stream>>>(row, cnt, rank, E);
        scan_pass1<<<NB, 1024, 0, stream>>>(cnt, rowstart, bsum, N);
        scan_pass2<<<1, 1024, 0, stream>>>(bsum, rowstart + N, NB);
        scan_pass3<<<512, 256, 0, stream>>>(rowstart, bsum, N);
        fill_csr<<<4096, 256, 0, stream>>>(row, col, vals, rowstart, rank, pairs, E);
        pull_rows<<<(N + 3) / 4, 256, 0, stream>>>(sup, pairs, rowstart, b, out, N);
    } else {
        init_out<<<2048, 256, 0, stream>>>(b, out, (long)N * (D / 4));
        long sthreads = (long)E * 32;
        scatter_edges<<<(int)((sthreads + 255) / 256), 256, 0, stream>>>(sup, row, col, vals, out, E);
    }
}

// Round 4
// 188.119 us; speedup vs baseline: 14.8633x; 1.7506x over previous
//
#include <hip/hip_runtime.h>

#define D 128       // D_IN == D_OUT
#define WPITCH 136  // Wt LDS pitch in bf16 elems: 272 B rows (16B-aligned, 2-way banks)

typedef __attribute__((ext_vector_type(8))) short short8;
typedef __attribute__((ext_vector_type(4))) float f32x4;

__device__ __forceinline__ unsigned short f2bf(float f) {  // RNE float->bf16
    unsigned u = __float_as_uint(f);
    u += 0x7FFF + ((u >> 16) & 1);
    return (unsigned short)(u >> 16);
}
__device__ __forceinline__ float bf2f(unsigned short b) {
    return __uint_as_float(((unsigned)b) << 16);
}

// ---------------------------------------------------------------------------
// Kernel 1: support = bf16(x) @ bf16(W) via MFMA, output bf16.
// 512 thr = 8 waves; wave = 16 rows x 128 cols (8 col-tiles, 4 k-chunks).
// W transposed into LDS as bf16 (Wt[col][k], pitch 136).
// ---------------------------------------------------------------------------
__global__ __launch_bounds__(512) void gemm_xw_mfma(const float* __restrict__ x,
                                                    const float* __restrict__ W,
                                                    unsigned short* __restrict__ sup,
                                                    int N) {
    __shared__ unsigned short Wt[128 * WPITCH];  // ~34.8 KB
    const int tid = threadIdx.x;
    for (int i = tid; i < 128 * 64; i += 512) {
        int c = i & 127, kp = i >> 7;  // col, k-pair
        unsigned pk = (unsigned)f2bf(W[(size_t)(2 * kp) * D + c]) |
                      ((unsigned)f2bf(W[(size_t)(2 * kp + 1) * D + c]) << 16);
        *(unsigned*)&Wt[c * WPITCH + 2 * kp] = pk;
    }
    __syncthreads();

    const int wid = tid >> 6, lane = tid & 63;
    const int row0 = blockIdx.x * 128 + wid * 16;
    if (row0 >= N) return;  // N % 16 == 0 for this problem; waves all-or-nothing
    const int fr = lane & 15, fq = lane >> 4;

    f32x4 acc[8];
#pragma unroll
    for (int t = 0; t < 8; ++t) acc[t] = (f32x4){0.f, 0.f, 0.f, 0.f};

    const float* xr = x + (size_t)(row0 + fr) * D + fq * 8;
#pragma unroll
    for (int kc = 0; kc < 4; ++kc) {
        float4 xa = *(const float4*)(xr + kc * 32);
        float4 xb = *(const float4*)(xr + kc * 32 + 4);
        short8 a;
        a[0] = (short)f2bf(xa.x); a[1] = (short)f2bf(xa.y);
        a[2] = (short)f2bf(xa.z); a[3] = (short)f2bf(xa.w);
        a[4] = (short)f2bf(xb.x); a[5] = (short)f2bf(xb.y);
        a[6] = (short)f2bf(xb.z); a[7] = (short)f2bf(xb.w);
        const int koff = kc * 32 + fq * 8;
#pragma unroll
        for (int ct = 0; ct < 8; ++ct) {
            short8 b = *(const short8*)&Wt[(ct * 16 + fr) * WPITCH + koff];
            acc[ct] = __builtin_amdgcn_mfma_f32_16x16x32_bf16(a, b, acc[ct], 0, 0, 0);
        }
    }

    // D[m][n]: m = row0 + fq*4 + j, n = ct*16 + fr. Pack col pairs via lane^1,
    // even lanes store j=0,1; odd lanes j=2,3 (balanced u32 stores).
    const int odd = fr & 1;
#pragma unroll
    for (int ct = 0; ct < 8; ++ct) {
#pragma unroll
        for (int j = 0; j < 4; ++j) {
            float mine = acc[ct][j];
            float oth = __shfl_xor(mine, 1, 64);
            unsigned lo = odd ? f2bf(oth) : f2bf(mine);
            unsigned hi = odd ? f2bf(mine) : f2bf(oth);
            unsigned pk = lo | (hi << 16);
            if ((j < 2) == (odd == 0)) {
                *(unsigned*)&sup[(size_t)(row0 + fq * 4 + j) * D + ct * 16 + (fr & ~1)] = pk;
            }
        }
    }
}

// ---------------------------------------------------------------------------
// Kernel 2: histogram + per-edge rank
// ---------------------------------------------------------------------------
__global__ __launch_bounds__(256) void hist_rows(const int* __restrict__ row,
                                                 int* __restrict__ cnt,
                                                 int* __restrict__ rank, int E) {
    int i = blockIdx.x * 256 + threadIdx.x;
    int stride = gridDim.x * 256;
    for (; i < E; i += stride) rank[i] = atomicAdd(&cnt[row[i]], 1);
}

// ---------------------------------------------------------------------------
// Kernel 3: multi-block exclusive scan
// ---------------------------------------------------------------------------
__device__ __forceinline__ int block_scan_1024(int v, int* wsum) {
    const int tid = threadIdx.x, lane = tid & 63, wid = tid >> 6;
    int s = v;
#pragma unroll
    for (int off = 1; off < 64; off <<= 1) {
        int t = __shfl_up(s, off, 64);
        if (lane >= off) s += t;
    }
    if (lane == 63) wsum[wid] = s;
    __syncthreads();
    if (wid == 0 && lane < 16) {
        int ws = wsum[lane];
#pragma unroll
        for (int off = 1; off < 16; off <<= 1) {
            int t = __shfl_up(ws, off, 64);
            if (lane >= off) ws += t;
        }
        wsum[lane] = ws;
    }
    __syncthreads();
    int waveoff = (wid == 0) ? 0 : wsum[wid - 1];
    return waveoff + s;
}

__global__ __launch_bounds__(1024) void scan_pass1(const int* __restrict__ cnt,
                                                   int* __restrict__ excl,
                                                   int* __restrict__ bsum, int N) {
    __shared__ int wsum[16];
    int i = blockIdx.x * 1024 + threadIdx.x;
    int v = (i < N) ? cnt[i] : 0;
    int incl = block_scan_1024(v, wsum);
    if (i < N) excl[i] = incl - v;
    if (threadIdx.x == 0) bsum[blockIdx.x] = wsum[15];
}

__global__ __launch_bounds__(1024) void scan_pass2(int* __restrict__ bsum,
                                                   int* __restrict__ rowN, int NB) {
    __shared__ int wsum[16];
    int tid = threadIdx.x;
    int v = (tid < NB) ? bsum[tid] : 0;
    int incl = block_scan_1024(v, wsum);
    if (tid < NB) bsum[tid] = incl - v;
    if (tid == 0) *rowN = wsum[15];
}

__global__ __launch_bounds__(256) void scan_pass3(int* __restrict__ excl,
                                                  const int* __restrict__ bsum, int N) {
    int i = blockIdx.x * 256 + threadIdx.x;
    int stride = gridDim.x * 256;
    for (; i < N; i += stride) excl[i] += bsum[i >> 10];
}

// ---------------------------------------------------------------------------
// Kernel 4: atomic-free bucket fill
// ---------------------------------------------------------------------------
__global__ __launch_bounds__(256) void fill_csr(const int* __restrict__ row,
                                                const int* __restrict__ col,
                                                const float* __restrict__ vals,
                                                const int* __restrict__ rowstart,
                                                const int* __restrict__ rank,
                                                int2* __restrict__ pairs, int E) {
    int i = blockIdx.x * 256 + threadIdx.x;
    int stride = gridDim.x * 256;
    for (; i < E; i += stride) {
        int r = row[i];
        int pos = rowstart[r] + rank[i];
        int2 pk;
        pk.x = col[i];
        pk.y = __float_as_int(vals[i]);
        pairs[pos] = pk;
    }
}

// ---------------------------------------------------------------------------
// Kernel 5: pull — wave per row, bf16 support gathers (u32/lane), x4 MLP
// ---------------------------------------------------------------------------
__global__ __launch_bounds__(256) void pull_rows(const unsigned short* __restrict__ sup,
                                                 const int2* __restrict__ pairs,
                                                 const int* __restrict__ rowstart,
                                                 const float* __restrict__ b,
                                                 float* __restrict__ out, int N) {
    int r = blockIdx.x * 4 + (threadIdx.x >> 6);
    if (r >= N) return;
    int lane = threadIdx.x & 63;
    int s = rowstart[r];
    int e = rowstart[r + 1];
    float2 acc = ((const float2*)b)[lane];

    for (int jb = s; jb < e; jb += 64) {
        int nb = min(64, e - jb);
        int2 pk = {0, 0};
        if (lane < nb) pk = pairs[jb + lane];

        int j = 0;
        for (; j + 4 <= nb; j += 4) {
            int c0 = __shfl(pk.x, j + 0, 64);
            int c1 = __shfl(pk.x, j + 1, 64);
            int c2 = __shfl(pk.x, j + 2, 64);
            int c3 = __shfl(pk.x, j + 3, 64);
            float v0 = __int_as_float(__shfl(pk.y, j + 0, 64));
            float v1 = __int_as_float(__shfl(pk.y, j + 1, 64));
            float v2 = __int_as_float(__shfl(pk.y, j + 2, 64));
            float v3 = __int_as_float(__shfl(pk.y, j + 3, 64));
            unsigned s0 = *(const unsigned*)&sup[(size_t)c0 * D + lane * 2];
            unsigned s1 = *(const unsigned*)&sup[(size_t)c1 * D + lane * 2];
            unsigned s2 = *(const unsigned*)&sup[(size_t)c2 * D + lane * 2];
            unsigned s3 = *(const unsigned*)&sup[(size_t)c3 * D + lane * 2];
            acc.x += v0 * bf2f((unsigned short)s0);
            acc.y += v0 * bf2f((unsigned short)(s0 >> 16));
            acc.x += v1 * bf2f((unsigned short)s1);
            acc.y += v1 * bf2f((unsigned short)(s1 >> 16));
            acc.x += v2 * bf2f((unsigned short)s2);
            acc.y += v2 * bf2f((unsigned short)(s2 >> 16));
            acc.x += v3 * bf2f((unsigned short)s3);
            acc.y += v3 * bf2f((unsigned short)(s3 >> 16));
        }
        for (; j < nb; ++j) {
            int c = __shfl(pk.x, j, 64);
            float v = __int_as_float(__shfl(pk.y, j, 64));
            unsigned sv = *(const unsigned*)&sup[(size_t)c * D + lane * 2];
            acc.x += v * bf2f((unsigned short)sv);
            acc.y += v * bf2f((unsigned short)(sv >> 16));
        }
    }
    ((float2*)(out + (size_t)r * D))[lane] = acc;
}

// ---------------------------------------------------------------------------
// Fallback (ws too small): atomic scatter from bf16 sup
// ---------------------------------------------------------------------------
__global__ __launch_bounds__(256) void init_out(const float* __restrict__ b,
                                                float* __restrict__ out,
                                                long total4) {
    const float4* b4 = (const float4*)b;
    long i = (long)blockIdx.x * blockDim.x + threadIdx.x;
    long stride = (long)gridDim.x * blockDim.x;
    for (; i < total4; i += stride) ((float4*)out)[i] = b4[i & 31];
}

__global__ __launch_bounds__(256) void scatter_edges(const unsigned short* __restrict__ sup,
                                                     const int* __restrict__ row,
                                                     const int* __restrict__ col,
                                                     const float* __restrict__ vals,
                                                     float* __restrict__ out, int E) {
    long gid = (long)blockIdx.x * 256 + threadIdx.x;
    int e = (int)(gid >> 5);
    if (e >= E) return;
    int p = (int)(gid & 31);
    int r = row[e];
    int c = col[e];
    float v = vals[e];
    unsigned sa = *(const unsigned*)&sup[(size_t)c * D + p * 4];
    unsigned sb = *(const unsigned*)&sup[(size_t)c * D + p * 4 + 2];
    float* o = out + (size_t)r * D + (size_t)p * 4;
    atomicAdd(o + 0, v * bf2f((unsigned short)sa));
    atomicAdd(o + 1, v * bf2f((unsigned short)(sa >> 16)));
    atomicAdd(o + 2, v * bf2f((unsigned short)sb));
    atomicAdd(o + 3, v * bf2f((unsigned short)(sb >> 16)));
}

extern "C" void kernel_launch(void* const* d_in, const int* in_sizes, int n_in,
                              void* d_out, int out_size, void* d_ws, size_t ws_size,
                              hipStream_t stream) {
    const float* x    = (const float*)d_in[0];
    const float* W    = (const float*)d_in[1];
    const float* b    = (const float*)d_in[2];
    const int*   row  = (const int*)d_in[3];
    const int*   col  = (const int*)d_in[4];
    const float* vals = (const float*)d_in[5];
    float* out = (float*)d_out;

    const int N = in_sizes[0] / D;
    const int E = in_sizes[3];
    const int NB = (N + 1023) / 1024;

    // workspace layout
    char* base = (char*)d_ws;
    size_t off = 0;
    unsigned short* sup = (unsigned short*)(base + off);
    off += (size_t)N * D * sizeof(unsigned short);
    off = (off + 7) & ~(size_t)7;
    int* cnt      = (int*)(base + off);  off += (size_t)N * sizeof(int);
    int* rowstart = (int*)(base + off);  off += (size_t)(N + 1) * sizeof(int);
    int* bsum     = (int*)(base + off);  off += (size_t)((NB + 1023) & ~1023) * sizeof(int);
    int* rank     = (int*)(base + off);  off += (size_t)E * sizeof(int);
    off = (off + 7) & ~(size_t)7;
    int2* pairs   = (int2*)(base + off); off += (size_t)E * sizeof(int2);
    const bool csr_ok = (off <= ws_size) && (NB <= 1024);

    gemm_xw_mfma<<<(N + 127) / 128, 512, 0, stream>>>(x, W, sup, N);

    if (csr_ok) {
        hipMemsetAsync(cnt, 0, (size_t)N * sizeof(int), stream);
        hist_rows<<<2048, 256, 0, stream>>>(row, cnt, rank, E);
        scan_pass1<<<NB, 1024, 0, stream>>>(cnt, rowstart, bsum, N);
        scan_pass2<<<1, 1024, 0, stream>>>(bsum, rowstart + N, NB);
        scan_pass3<<<512, 256, 0, stream>>>(rowstart, bsum, N);
        fill_csr<<<4096, 256, 0, stream>>>(row, col, vals, rowstart, rank, pairs, E);
        pull_rows<<<(N + 3) / 4, 256, 0, stream>>>(sup, pairs, rowstart, b, out, N);
    } else {
        init_out<<<2048, 256, 0, stream>>>(b, out, (long)N * (D / 4));
        long sthreads = (long)E * 32;
        scatter_edges<<<(int)((sthreads + 255) / 256), 256, 0, stream>>>(sup, row, col, vals, out, E);
    }
}

// Round 5
// 186.657 us; speedup vs baseline: 14.9797x; 1.0078x over previous
//
#include <hip/hip_runtime.h>

#define D 128       // D_IN == D_OUT
#define WPITCH 136  // Wt LDS pitch in bf16 elems
#define CPAD 16     // cnt padding: one counter per 64B line

typedef __attribute__((ext_vector_type(8))) short short8;
typedef __attribute__((ext_vector_type(4))) float f32x4;

__device__ __forceinline__ unsigned short f2bf(float f) {  // RNE float->bf16
    unsigned u = __float_as_uint(f);
    u += 0x7FFF + ((u >> 16) & 1);
    return (unsigned short)(u >> 16);
}
__device__ __forceinline__ float bf2f(unsigned short b) {
    return __uint_as_float(((unsigned)b) << 16);
}

// ---------------------------------------------------------------------------
// gemm block body: 128 rows of sup = bf16(x) @ bf16(W), 8 waves/block
// ---------------------------------------------------------------------------
__device__ __forceinline__ void gemm_block(const float* __restrict__ x,
                                           const float* __restrict__ W,
                                           unsigned short* __restrict__ sup,
                                           int N, int bid, unsigned short* Wt) {
    const int tid = threadIdx.x;
    for (int i = tid; i < 128 * 64; i += 512) {
        int c = i & 127, kp = i >> 7;
        unsigned pk = (unsigned)f2bf(W[(size_t)(2 * kp) * D + c]) |
                      ((unsigned)f2bf(W[(size_t)(2 * kp + 1) * D + c]) << 16);
        *(unsigned*)&Wt[c * WPITCH + 2 * kp] = pk;
    }
    __syncthreads();

    const int wid = tid >> 6, lane = tid & 63;
    const int row0 = bid * 128 + wid * 16;
    if (row0 >= N) return;
    const int fr = lane & 15, fq = lane >> 4;

    f32x4 acc[8];
#pragma unroll
    for (int t = 0; t < 8; ++t) acc[t] = (f32x4){0.f, 0.f, 0.f, 0.f};

    const float* xr = x + (size_t)(row0 + fr) * D + fq * 8;
#pragma unroll
    for (int kc = 0; kc < 4; ++kc) {
        float4 xa = *(const float4*)(xr + kc * 32);
        float4 xb = *(const float4*)(xr + kc * 32 + 4);
        short8 a;
        a[0] = (short)f2bf(xa.x); a[1] = (short)f2bf(xa.y);
        a[2] = (short)f2bf(xa.z); a[3] = (short)f2bf(xa.w);
        a[4] = (short)f2bf(xb.x); a[5] = (short)f2bf(xb.y);
        a[6] = (short)f2bf(xb.z); a[7] = (short)f2bf(xb.w);
        const int koff = kc * 32 + fq * 8;
#pragma unroll
        for (int ct = 0; ct < 8; ++ct) {
            short8 b = *(const short8*)&Wt[(ct * 16 + fr) * WPITCH + koff];
            acc[ct] = __builtin_amdgcn_mfma_f32_16x16x32_bf16(a, b, acc[ct], 0, 0, 0);
        }
    }

    const int odd = fr & 1;
#pragma unroll
    for (int ct = 0; ct < 8; ++ct) {
#pragma unroll
        for (int j = 0; j < 4; ++j) {
            float mine = acc[ct][j];
            float oth = __shfl_xor(mine, 1, 64);
            unsigned lo = odd ? f2bf(oth) : f2bf(mine);
            unsigned hi = odd ? f2bf(mine) : f2bf(oth);
            unsigned pk = lo | (hi << 16);
            if ((j < 2) == (odd == 0)) {
                *(unsigned*)&sup[(size_t)(row0 + fq * 4 + j) * D + ct * 16 + (fr & ~1)] = pk;
            }
        }
    }
}

// ---------------------------------------------------------------------------
// Fused kernel: blocks [0,NG) = gemm; blocks [NG, NG+NH) = histogram+rank.
// hist: 4 independent atomics in flight per thread; cnt padded to 64B lines.
// ---------------------------------------------------------------------------
__global__ __launch_bounds__(512) void gemm_hist(const float* __restrict__ x,
                                                 const float* __restrict__ W,
                                                 unsigned short* __restrict__ sup,
                                                 int N, int NG,
                                                 const int* __restrict__ row,
                                                 int* __restrict__ cnt,
                                                 int* __restrict__ rank, int E) {
    __shared__ unsigned short Wt[128 * WPITCH];
    if ((int)blockIdx.x < NG) {
        gemm_block(x, W, sup, N, blockIdx.x, Wt);
        return;
    }
    const int hb = blockIdx.x - NG;
    const int base = hb * 2048 + threadIdx.x;
    int i0 = base, i1 = base + 512, i2 = base + 1024, i3 = base + 1536;
    int r0 = (i0 < E) ? row[i0] : -1;
    int r1 = (i1 < E) ? row[i1] : -1;
    int r2 = (i2 < E) ? row[i2] : -1;
    int r3 = (i3 < E) ? row[i3] : -1;
    int k0 = 0, k1 = 0, k2 = 0, k3 = 0;
    if (r0 >= 0) k0 = atomicAdd(&cnt[(size_t)r0 * CPAD], 1);
    if (r1 >= 0) k1 = atomicAdd(&cnt[(size_t)r1 * CPAD], 1);
    if (r2 >= 0) k2 = atomicAdd(&cnt[(size_t)r2 * CPAD], 1);
    if (r3 >= 0) k3 = atomicAdd(&cnt[(size_t)r3 * CPAD], 1);
    if (r0 >= 0) rank[i0] = k0;
    if (r1 >= 0) rank[i1] = k1;
    if (r2 >= 0) rank[i2] = k2;
    if (r3 >= 0) rank[i3] = k3;
}

// standalone gemm (fallback path)
__global__ __launch_bounds__(512) void gemm_only(const float* __restrict__ x,
                                                 const float* __restrict__ W,
                                                 unsigned short* __restrict__ sup, int N) {
    __shared__ unsigned short Wt[128 * WPITCH];
    gemm_block(x, W, sup, N, blockIdx.x, Wt);
}

// ---------------------------------------------------------------------------
// Multi-block exclusive scan over padded cnt
// ---------------------------------------------------------------------------
__device__ __forceinline__ int block_scan_1024(int v, int* wsum) {
    const int tid = threadIdx.x, lane = tid & 63, wid = tid >> 6;
    int s = v;
#pragma unroll
    for (int off = 1; off < 64; off <<= 1) {
        int t = __shfl_up(s, off, 64);
        if (lane >= off) s += t;
    }
    if (lane == 63) wsum[wid] = s;
    __syncthreads();
    if (wid == 0 && lane < 16) {
        int ws = wsum[lane];
#pragma unroll
        for (int off = 1; off < 16; off <<= 1) {
            int t = __shfl_up(ws, off, 64);
            if (lane >= off) ws += t;
        }
        wsum[lane] = ws;
    }
    __syncthreads();
    int waveoff = (wid == 0) ? 0 : wsum[wid - 1];
    return waveoff + s;
}

__global__ __launch_bounds__(1024) void scan_pass1(const int* __restrict__ cnt,
                                                   int* __restrict__ excl,
                                                   int* __restrict__ bsum, int N) {
    __shared__ int wsum[16];
    int i = blockIdx.x * 1024 + threadIdx.x;
    int v = (i < N) ? cnt[(size_t)i * CPAD] : 0;
    int incl = block_scan_1024(v, wsum);
    if (i < N) excl[i] = incl - v;
    if (threadIdx.x == 0) bsum[blockIdx.x] = wsum[15];
}

__global__ __launch_bounds__(1024) void scan_pass2(int* __restrict__ bsum,
                                                   int* __restrict__ rowN, int NB) {
    __shared__ int wsum[16];
    int tid = threadIdx.x;
    int v = (tid < NB) ? bsum[tid] : 0;
    int incl = block_scan_1024(v, wsum);
    if (tid < NB) bsum[tid] = incl - v;
    if (tid == 0) *rowN = wsum[15];
}

__global__ __launch_bounds__(256) void scan_pass3(int* __restrict__ excl,
                                                  const int* __restrict__ bsum, int N) {
    int i = blockIdx.x * 256 + threadIdx.x;
    int stride = gridDim.x * 256;
    for (; i < N; i += stride) excl[i] += bsum[i >> 10];
}

// ---------------------------------------------------------------------------
// Atomic-free bucket fill
// ---------------------------------------------------------------------------
__global__ __launch_bounds__(256) void fill_csr(const int* __restrict__ row,
                                                const int* __restrict__ col,
                                                const float* __restrict__ vals,
                                                const int* __restrict__ rowstart,
                                                const int* __restrict__ rank,
                                                int2* __restrict__ pairs, int E) {
    int i = blockIdx.x * 256 + threadIdx.x;
    int stride = gridDim.x * 256;
    for (; i < E; i += stride) {
        int r = row[i];
        int pos = rowstart[r] + rank[i];
        int2 pk;
        pk.x = col[i];
        pk.y = __float_as_int(vals[i]);
        pairs[pos] = pk;
    }
}

// ---------------------------------------------------------------------------
// Pull: wave per row, bf16 support gathers, x4 unroll
// ---------------------------------------------------------------------------
__global__ __launch_bounds__(256) void pull_rows(const unsigned short* __restrict__ sup,
                                                 const int2* __restrict__ pairs,
                                                 const int* __restrict__ rowstart,
                                                 const float* __restrict__ b,
                                                 float* __restrict__ out, int N) {
    int r = blockIdx.x * 4 + (threadIdx.x >> 6);
    if (r >= N) return;
    int lane = threadIdx.x & 63;
    int s = rowstart[r];
    int e = rowstart[r + 1];
    float2 acc = ((const float2*)b)[lane];

    for (int jb = s; jb < e; jb += 64) {
        int nb = min(64, e - jb);
        int2 pk = {0, 0};
        if (lane < nb) pk = pairs[jb + lane];

        int j = 0;
        for (; j + 4 <= nb; j += 4) {
            int c0 = __shfl(pk.x, j + 0, 64);
            int c1 = __shfl(pk.x, j + 1, 64);
            int c2 = __shfl(pk.x, j + 2, 64);
            int c3 = __shfl(pk.x, j + 3, 64);
            float v0 = __int_as_float(__shfl(pk.y, j + 0, 64));
            float v1 = __int_as_float(__shfl(pk.y, j + 1, 64));
            float v2 = __int_as_float(__shfl(pk.y, j + 2, 64));
            float v3 = __int_as_float(__shfl(pk.y, j + 3, 64));
            unsigned s0 = *(const unsigned*)&sup[(size_t)c0 * D + lane * 2];
            unsigned s1 = *(const unsigned*)&sup[(size_t)c1 * D + lane * 2];
            unsigned s2 = *(const unsigned*)&sup[(size_t)c2 * D + lane * 2];
            unsigned s3 = *(const unsigned*)&sup[(size_t)c3 * D + lane * 2];
            acc.x += v0 * bf2f((unsigned short)s0);
            acc.y += v0 * bf2f((unsigned short)(s0 >> 16));
            acc.x += v1 * bf2f((unsigned short)s1);
            acc.y += v1 * bf2f((unsigned short)(s1 >> 16));
            acc.x += v2 * bf2f((unsigned short)s2);
            acc.y += v2 * bf2f((unsigned short)(s2 >> 16));
            acc.x += v3 * bf2f((unsigned short)s3);
            acc.y += v3 * bf2f((unsigned short)(s3 >> 16));
        }
        for (; j < nb; ++j) {
            int c = __shfl(pk.x, j, 64);
            float v = __int_as_float(__shfl(pk.y, j, 64));
            unsigned sv = *(const unsigned*)&sup[(size_t)c * D + lane * 2];
            acc.x += v * bf2f((unsigned short)sv);
            acc.y += v * bf2f((unsigned short)(sv >> 16));
        }
    }
    ((float2*)(out + (size_t)r * D))[lane] = acc;
}

// ---------------------------------------------------------------------------
// Fallback: atomic scatter from bf16 sup
// ---------------------------------------------------------------------------
__global__ __launch_bounds__(256) void init_out(const float* __restrict__ b,
                                                float* __restrict__ out,
                                                long total4) {
    const float4* b4 = (const float4*)b;
    long i = (long)blockIdx.x * blockDim.x + threadIdx.x;
    long stride = (long)gridDim.x * blockDim.x;
    for (; i < total4; i += stride) ((float4*)out)[i] = b4[i & 31];
}

__global__ __launch_bounds__(256) void scatter_edges(const unsigned short* __restrict__ sup,
                                                     const int* __restrict__ row,
                                                     const int* __restrict__ col,
                                                     const float* __restrict__ vals,
                                                     float* __restrict__ out, int E) {
    long gid = (long)blockIdx.x * 256 + threadIdx.x;
    int e = (int)(gid >> 5);
    if (e >= E) return;
    int p = (int)(gid & 31);
    int r = row[e];
    int c = col[e];
    float v = vals[e];
    unsigned sa = *(const unsigned*)&sup[(size_t)c * D + p * 4];
    unsigned sb = *(const unsigned*)&sup[(size_t)c * D + p * 4 + 2];
    float* o = out + (size_t)r * D + (size_t)p * 4;
    atomicAdd(o + 0, v * bf2f((unsigned short)sa));
    atomicAdd(o + 1, v * bf2f((unsigned short)(sa >> 16)));
    atomicAdd(o + 2, v * bf2f((unsigned short)sb));
    atomicAdd(o + 3, v * bf2f((unsigned short)(sb >> 16)));
}

extern "C" void kernel_launch(void* const* d_in, const int* in_sizes, int n_in,
                              void* d_out, int out_size, void* d_ws, size_t ws_size,
                              hipStream_t stream) {
    const float* x    = (const float*)d_in[0];
    const float* W    = (const float*)d_in[1];
    const float* b    = (const float*)d_in[2];
    const int*   row  = (const int*)d_in[3];
    const int*   col  = (const int*)d_in[4];
    const float* vals = (const float*)d_in[5];
    float* out = (float*)d_out;

    const int N = in_sizes[0] / D;
    const int E = in_sizes[3];
    const int NB = (N + 1023) / 1024;
    const int NG = (N + 127) / 128;    // gemm blocks
    const int NH = (E + 2047) / 2048;  // hist blocks (4 edges / thread, 512 thr)

    // workspace layout
    char* base = (char*)d_ws;
    size_t off = 0;
    unsigned short* sup = (unsigned short*)(base + off);
    off += (size_t)N * D * sizeof(unsigned short);
    off = (off + 63) & ~(size_t)63;
    int* cnt      = (int*)(base + off);  off += (size_t)N * CPAD * sizeof(int);  // 64B/row
    int* rowstart = (int*)(base + off);  off += (size_t)(N + 1) * sizeof(int);
    int* bsum     = (int*)(base + off);  off += (size_t)((NB + 1023) & ~1023) * sizeof(int);
    int* rank     = (int*)(base + off);  off += (size_t)E * sizeof(int);
    off = (off + 7) & ~(size_t)7;
    int2* pairs   = (int2*)(base + off); off += (size_t)E * sizeof(int2);
    const bool csr_ok = (off <= ws_size) && (NB <= 1024);

    if (csr_ok) {
        hipMemsetAsync(cnt, 0, (size_t)N * CPAD * sizeof(int), stream);
        gemm_hist<<<NG + NH, 512, 0, stream>>>(x, W, sup, N, NG, row, cnt, rank, E);
        scan_pass1<<<NB, 1024, 0, stream>>>(cnt, rowstart, bsum, N);
        scan_pass2<<<1, 1024, 0, stream>>>(bsum, rowstart + N, NB);
        scan_pass3<<<512, 256, 0, stream>>>(rowstart, bsum, N);
        fill_csr<<<4096, 256, 0, stream>>>(row, col, vals, rowstart, rank, pairs, E);
        pull_rows<<<(N + 3) / 4, 256, 0, stream>>>(sup, pairs, rowstart, b, out, N);
    } else {
        gemm_only<<<NG, 512, 0, stream>>>(x, W, sup, N);
        init_out<<<2048, 256, 0, stream>>>(b, out, (long)N * (D / 4));
        long sthreads = (long)E * 32;
        scatter_edges<<<(int)((sthreads + 255) / 256), 256, 0, stream>>>(sup, row, col, vals, out, E);
    }
}

// Round 6
// 139.206 us; speedup vs baseline: 20.0858x; 1.3409x over previous
//
#include <hip/hip_runtime.h>

#define D 128       // D_IN == D_OUT
#define WPITCH 136  // Wt LDS pitch in bf16 elems
#define CH 8192     // edges per binning block
#define MAXB 1024   // max coarse buckets (N <= 131072)

typedef __attribute__((ext_vector_type(8))) short short8;
typedef __attribute__((ext_vector_type(4))) float f32x4;

__device__ __forceinline__ unsigned short f2bf(float f) {  // RNE float->bf16
    unsigned u = __float_as_uint(f);
    u += 0x7FFF + ((u >> 16) & 1);
    return (unsigned short)(u >> 16);
}
__device__ __forceinline__ float bf2f(unsigned short b) {
    return __uint_as_float(((unsigned)b) << 16);
}

// ---------------------------------------------------------------------------
// gemm block body: 128 rows of sup = bf16(x) @ bf16(W), 8 waves/block
// ---------------------------------------------------------------------------
__device__ __forceinline__ void gemm_block(const float* __restrict__ x,
                                           const float* __restrict__ W,
                                           unsigned short* __restrict__ sup,
                                           int N, int bid, unsigned short* Wt) {
    const int tid = threadIdx.x;
    for (int i = tid; i < 128 * 64; i += 512) {
        int c = i & 127, kp = i >> 7;
        unsigned pk = (unsigned)f2bf(W[(size_t)(2 * kp) * D + c]) |
                      ((unsigned)f2bf(W[(size_t)(2 * kp + 1) * D + c]) << 16);
        *(unsigned*)&Wt[c * WPITCH + 2 * kp] = pk;
    }
    __syncthreads();

    const int wid = tid >> 6, lane = tid & 63;
    const int row0 = bid * 128 + wid * 16;
    if (row0 >= N) return;
    const int fr = lane & 15, fq = lane >> 4;

    f32x4 acc[8];
#pragma unroll
    for (int t = 0; t < 8; ++t) acc[t] = (f32x4){0.f, 0.f, 0.f, 0.f};

    const float* xr = x + (size_t)(row0 + fr) * D + fq * 8;
#pragma unroll
    for (int kc = 0; kc < 4; ++kc) {
        float4 xa = *(const float4*)(xr + kc * 32);
        float4 xb = *(const float4*)(xr + kc * 32 + 4);
        short8 a;
        a[0] = (short)f2bf(xa.x); a[1] = (short)f2bf(xa.y);
        a[2] = (short)f2bf(xa.z); a[3] = (short)f2bf(xa.w);
        a[4] = (short)f2bf(xb.x); a[5] = (short)f2bf(xb.y);
        a[6] = (short)f2bf(xb.z); a[7] = (short)f2bf(xb.w);
        const int koff = kc * 32 + fq * 8;
#pragma unroll
        for (int ct = 0; ct < 8; ++ct) {
            short8 b = *(const short8*)&Wt[(ct * 16 + fr) * WPITCH + koff];
            acc[ct] = __builtin_amdgcn_mfma_f32_16x16x32_bf16(a, b, acc[ct], 0, 0, 0);
        }
    }

    const int odd = fr & 1;
#pragma unroll
    for (int ct = 0; ct < 8; ++ct) {
#pragma unroll
        for (int j = 0; j < 4; ++j) {
            float mine = acc[ct][j];
            float oth = __shfl_xor(mine, 1, 64);
            unsigned lo = odd ? f2bf(oth) : f2bf(mine);
            unsigned hi = odd ? f2bf(mine) : f2bf(oth);
            unsigned pk = lo | (hi << 16);
            if ((j < 2) == (odd == 0)) {
                *(unsigned*)&sup[(size_t)(row0 + fq * 4 + j) * D + ct * 16 + (fr & ~1)] = pk;
            }
        }
    }
}

// ---------------------------------------------------------------------------
// Fused: blocks [0,NG) gemm; [NG,NG+NA) coarse bucket count (A1).
// A1: LDS histogram over NBUCK buckets, then <=NBUCK non-returning global adds.
// ---------------------------------------------------------------------------
__global__ __launch_bounds__(512) void gemm_binA(const float* __restrict__ x,
                                                 const float* __restrict__ W,
                                                 unsigned short* __restrict__ sup,
                                                 int N, int NG,
                                                 const int* __restrict__ row,
                                                 int* __restrict__ bucketCnt,
                                                 int E, int NBUCK) {
    __shared__ unsigned short Wt[128 * WPITCH];
    __shared__ int lcnt[MAXB];
    if ((int)blockIdx.x < NG) {
        gemm_block(x, W, sup, N, blockIdx.x, Wt);
        return;
    }
    const int tid = threadIdx.x;
    for (int t = tid; t < NBUCK; t += 512) lcnt[t] = 0;
    __syncthreads();
    const int base = (blockIdx.x - NG) * CH;
#pragma unroll
    for (int k = 0; k < CH / 512; ++k) {
        int i = base + k * 512 + tid;
        if (i < E) atomicAdd(&lcnt[row[i] >> 7], 1);
    }
    __syncthreads();
    for (int t = tid; t < NBUCK; t += 512) {
        int c = lcnt[t];
        if (c) atomicAdd(&bucketCnt[t], c);  // non-returning
    }
}

// standalone gemm (fallback path)
__global__ __launch_bounds__(512) void gemm_only(const float* __restrict__ x,
                                                 const float* __restrict__ W,
                                                 unsigned short* __restrict__ sup, int N) {
    __shared__ unsigned short Wt[128 * WPITCH];
    gemm_block(x, W, sup, N, blockIdx.x, Wt);
}

// ---------------------------------------------------------------------------
// Scan bucket counts -> bucketStart / gCursor; rowstart[N] = E.
// ---------------------------------------------------------------------------
__device__ __forceinline__ int block_scan_1024(int v, int* wsum) {
    const int tid = threadIdx.x, lane = tid & 63, wid = tid >> 6;
    int s = v;
#pragma unroll
    for (int off = 1; off < 64; off <<= 1) {
        int t = __shfl_up(s, off, 64);
        if (lane >= off) s += t;
    }
    if (lane == 63) wsum[wid] = s;
    __syncthreads();
    if (wid == 0 && lane < 16) {
        int ws = wsum[lane];
#pragma unroll
        for (int off = 1; off < 16; off <<= 1) {
            int t = __shfl_up(ws, off, 64);
            if (lane >= off) ws += t;
        }
        wsum[lane] = ws;
    }
    __syncthreads();
    int waveoff = (wid == 0) ? 0 : wsum[wid - 1];
    return waveoff + s;
}

__global__ __launch_bounds__(1024) void scan_buckets(const int* __restrict__ bucketCnt,
                                                     int* __restrict__ bucketStart,
                                                     int* __restrict__ gCursor,
                                                     int* __restrict__ rowstartN,
                                                     int NBUCK, int E) {
    __shared__ int wsum[16];
    int tid = threadIdx.x;
    int v = (tid < NBUCK) ? bucketCnt[tid] : 0;
    int incl = block_scan_1024(v, wsum);
    int excl = incl - v;
    if (tid < NBUCK) { bucketStart[tid] = excl; gCursor[tid] = excl; }
    if (tid == 0) { bucketStart[NBUCK] = wsum[15]; *rowstartN = E; }
}

// ---------------------------------------------------------------------------
// A2: per 8192-edge block: LDS count -> per-bucket segment claim (returning
// atomic per block-bucket) -> LDS rank -> scatter packed (col|rlow<<20, val).
// ---------------------------------------------------------------------------
__global__ __launch_bounds__(512) void bin_scatter(const int* __restrict__ row,
                                                   const int* __restrict__ col,
                                                   const float* __restrict__ vals,
                                                   int* __restrict__ gCursor,
                                                   int2* __restrict__ pairs0,
                                                   int E, int NBUCK) {
    __shared__ int lcnt[MAXB];
    __shared__ int lbase[MAXB];
    const int tid = threadIdx.x;
    for (int t = tid; t < NBUCK; t += 512) lcnt[t] = 0;
    __syncthreads();
    const int base = blockIdx.x * CH;
#pragma unroll
    for (int k = 0; k < CH / 512; ++k) {
        int i = base + k * 512 + tid;
        if (i < E) atomicAdd(&lcnt[row[i] >> 7], 1);
    }
    __syncthreads();
    for (int t = tid; t < NBUCK; t += 512) {
        int c = lcnt[t];
        lbase[t] = c ? atomicAdd(&gCursor[t], c) : 0;
        lcnt[t] = 0;
    }
    __syncthreads();
#pragma unroll
    for (int k = 0; k < CH / 512; ++k) {
        int i = base + k * 512 + tid;
        if (i < E) {
            int r = row[i];
            int bk = r >> 7;
            int rk = atomicAdd(&lcnt[bk], 1);
            int2 q;
            q.x = col[i] | ((r & 127) << 20);
            q.y = __float_as_int(vals[i]);
            pairs0[lbase[bk] + rk] = q;
        }
    }
}

// ---------------------------------------------------------------------------
// B: one block per bucket. LDS fine-hist over 128 rows -> scan -> rowstart,
// rank pass -> row-grouped pairs (clean col).
// ---------------------------------------------------------------------------
__global__ __launch_bounds__(256) void bucket_csr(const int2* __restrict__ pairs0,
                                                  const int* __restrict__ bucketStart,
                                                  int* __restrict__ rowstart,
                                                  int2* __restrict__ pairs, int N) {
    __shared__ int lcnt[128], lofs[128];
    const int t = blockIdx.x;
    const int tid = threadIdx.x;
    const int s = bucketStart[t], e = bucketStart[t + 1];
    if (tid < 128) lcnt[tid] = 0;
    __syncthreads();
    for (int i = s + tid; i < e; i += 256) {
        unsigned px = (unsigned)pairs0[i].x;
        atomicAdd(&lcnt[(px >> 20) & 127], 1);
    }
    __syncthreads();
    if (tid < 128) lofs[tid] = lcnt[tid];
    for (int d = 1; d < 128; d <<= 1) {  // Hillis-Steele inclusive scan
        __syncthreads();
        int v = 0;
        if (tid < 128 && tid >= d) v = lofs[tid - d];
        __syncthreads();
        if (tid < 128) lofs[tid] += v;
    }
    __syncthreads();
    if (tid < 128) {
        int excl = lofs[tid] - lcnt[tid];
        int g = t * 128 + tid;
        if (g < N) rowstart[g] = s + excl;
        lofs[tid] = excl;
        lcnt[tid] = 0;
    }
    __syncthreads();
    for (int i = s + tid; i < e; i += 256) {
        int2 p = pairs0[i];
        unsigned px = (unsigned)p.x;
        int r = (px >> 20) & 127;
        int rk = atomicAdd(&lcnt[r], 1);
        int2 q;
        q.x = (int)(px & 0xFFFFF);
        q.y = p.y;
        pairs[s + lofs[r] + rk] = q;
    }
}

// ---------------------------------------------------------------------------
// Pull: wave per row, bf16 support gathers, x4 unroll
// ---------------------------------------------------------------------------
__global__ __launch_bounds__(256) void pull_rows(const unsigned short* __restrict__ sup,
                                                 const int2* __restrict__ pairs,
                                                 const int* __restrict__ rowstart,
                                                 const float* __restrict__ b,
                                                 float* __restrict__ out, int N) {
    int r = blockIdx.x * 4 + (threadIdx.x >> 6);
    if (r >= N) return;
    int lane = threadIdx.x & 63;
    int s = rowstart[r];
    int e = rowstart[r + 1];
    float2 acc = ((const float2*)b)[lane];

    for (int jb = s; jb < e; jb += 64) {
        int nb = min(64, e - jb);
        int2 pk = {0, 0};
        if (lane < nb) pk = pairs[jb + lane];

        int j = 0;
        for (; j + 4 <= nb; j += 4) {
            int c0 = __shfl(pk.x, j + 0, 64);
            int c1 = __shfl(pk.x, j + 1, 64);
            int c2 = __shfl(pk.x, j + 2, 64);
            int c3 = __shfl(pk.x, j + 3, 64);
            float v0 = __int_as_float(__shfl(pk.y, j + 0, 64));
            float v1 = __int_as_float(__shfl(pk.y, j + 1, 64));
            float v2 = __int_as_float(__shfl(pk.y, j + 2, 64));
            float v3 = __int_as_float(__shfl(pk.y, j + 3, 64));
            unsigned s0 = *(const unsigned*)&sup[(size_t)c0 * D + lane * 2];
            unsigned s1 = *(const unsigned*)&sup[(size_t)c1 * D + lane * 2];
            unsigned s2 = *(const unsigned*)&sup[(size_t)c2 * D + lane * 2];
            unsigned s3 = *(const unsigned*)&sup[(size_t)c3 * D + lane * 2];
            acc.x += v0 * bf2f((unsigned short)s0);
            acc.y += v0 * bf2f((unsigned short)(s0 >> 16));
            acc.x += v1 * bf2f((unsigned short)s1);
            acc.y += v1 * bf2f((unsigned short)(s1 >> 16));
            acc.x += v2 * bf2f((unsigned short)s2);
            acc.y += v2 * bf2f((unsigned short)(s2 >> 16));
            acc.x += v3 * bf2f((unsigned short)s3);
            acc.y += v3 * bf2f((unsigned short)(s3 >> 16));
        }
        for (; j < nb; ++j) {
            int c = __shfl(pk.x, j, 64);
            float v = __int_as_float(__shfl(pk.y, j, 64));
            unsigned sv = *(const unsigned*)&sup[(size_t)c * D + lane * 2];
            acc.x += v * bf2f((unsigned short)sv);
            acc.y += v * bf2f((unsigned short)(sv >> 16));
        }
    }
    ((float2*)(out + (size_t)r * D))[lane] = acc;
}

// ---------------------------------------------------------------------------
// Fallback: atomic scatter from bf16 sup
// ---------------------------------------------------------------------------
__global__ __launch_bounds__(256) void init_out(const float* __restrict__ b,
                                                float* __restrict__ out,
                                                long total4) {
    const float4* b4 = (const float4*)b;
    long i = (long)blockIdx.x * blockDim.x + threadIdx.x;
    long stride = (long)gridDim.x * blockDim.x;
    for (; i < total4; i += stride) ((float4*)out)[i] = b4[i & 31];
}

__global__ __launch_bounds__(256) void scatter_edges(const unsigned short* __restrict__ sup,
                                                     const int* __restrict__ row,
                                                     const int* __restrict__ col,
                                                     const float* __restrict__ vals,
                                                     float* __restrict__ out, int E) {
    long gid = (long)blockIdx.x * 256 + threadIdx.x;
    int e = (int)(gid >> 5);
    if (e >= E) return;
    int p = (int)(gid & 31);
    int r = row[e];
    int c = col[e];
    float v = vals[e];
    unsigned sa = *(const unsigned*)&sup[(size_t)c * D + p * 4];
    unsigned sb = *(const unsigned*)&sup[(size_t)c * D + p * 4 + 2];
    float* o = out + (size_t)r * D + (size_t)p * 4;
    atomicAdd(o + 0, v * bf2f((unsigned short)sa));
    atomicAdd(o + 1, v * bf2f((unsigned short)(sa >> 16)));
    atomicAdd(o + 2, v * bf2f((unsigned short)sb));
    atomicAdd(o + 3, v * bf2f((unsigned short)(sb >> 16)));
}

extern "C" void kernel_launch(void* const* d_in, const int* in_sizes, int n_in,
                              void* d_out, int out_size, void* d_ws, size_t ws_size,
                              hipStream_t stream) {
    const float* x    = (const float*)d_in[0];
    const float* W    = (const float*)d_in[1];
    const float* b    = (const float*)d_in[2];
    const int*   row  = (const int*)d_in[3];
    const int*   col  = (const int*)d_in[4];
    const float* vals = (const float*)d_in[5];
    float* out = (float*)d_out;

    const int N = in_sizes[0] / D;
    const int E = in_sizes[3];
    const int NG = (N + 127) / 128;     // gemm blocks
    const int NA = (E + CH - 1) / CH;   // binning blocks
    const int NBUCK = (N + 127) / 128;  // coarse buckets (128 rows each)

    // workspace layout
    char* base = (char*)d_ws;
    size_t off = 0;
    unsigned short* sup = (unsigned short*)(base + off);
    off += (size_t)N * D * sizeof(unsigned short);
    off = (off + 63) & ~(size_t)63;
    int* bucketCnt   = (int*)(base + off);  off += (size_t)MAXB * sizeof(int);
    int* bucketStart = (int*)(base + off);  off += (size_t)(MAXB + 1) * sizeof(int);
    int* gCursor     = (int*)(base + off);  off += (size_t)MAXB * sizeof(int);
    int* rowstart    = (int*)(base + off);  off += (size_t)(N + 1) * sizeof(int);
    off = (off + 7) & ~(size_t)7;
    int2* pairs0     = (int2*)(base + off); off += (size_t)E * sizeof(int2);
    int2* pairs      = (int2*)(base + off); off += (size_t)E * sizeof(int2);
    const bool csr_ok = (off <= ws_size) && (NBUCK <= MAXB) && (N <= (1 << 20));

    if (csr_ok) {
        hipMemsetAsync(bucketCnt, 0, (size_t)NBUCK * sizeof(int), stream);
        gemm_binA<<<NG + NA, 512, 0, stream>>>(x, W, sup, N, NG, row, bucketCnt, E, NBUCK);
        scan_buckets<<<1, 1024, 0, stream>>>(bucketCnt, bucketStart, gCursor, rowstart + N, NBUCK, E);
        bin_scatter<<<NA, 512, 0, stream>>>(row, col, vals, gCursor, pairs0, E, NBUCK);
        bucket_csr<<<NBUCK, 256, 0, stream>>>(pairs0, bucketStart, rowstart, pairs, N);
        pull_rows<<<(N + 3) / 4, 256, 0, stream>>>(sup, pairs, rowstart, b, out, N);
    } else {
        gemm_only<<<NG, 512, 0, stream>>>(x, W, sup, N);
        init_out<<<2048, 256, 0, stream>>>(b, out, (long)N * (D / 4));
        long sthreads = (long)E * 32;
        scatter_edges<<<(int)((sthreads + 255) / 256), 256, 0, stream>>>(sup, row, col, vals, out, E);
    }
}